// Round 5
// baseline (99.172 us; speedup 1.0000x reference)
//
#include <hip/hip_runtime.h>
#include <cstdint>
#include <cstddef>

// Problem constants (reference: N=8192, C=1000, A=768)
#define N_SAMPLES 8192
#define N_CLASSES 1000
#define C_PAD     1024
#define A_DIM     768
#define K_DIM     1536   // 2*A  (concatenated [u ; v] / [W^2 ; W])
#define BM 256
#define BN 128
#define BK 64
#define NT (K_DIM / BK)  // 24 K-steps
#define NBLK_SM (N_SAMPLES / 4)   // 2048 softmax blocks (4 rows each)

typedef __attribute__((ext_vector_type(8))) __bf16 bf16x8;
typedef __attribute__((ext_vector_type(4))) __bf16 bf16x4;
typedef __attribute__((ext_vector_type(4))) float  f32x4;

#define WAIT_VM(N) do { asm volatile("s_waitcnt vmcnt(" #N ")" ::: "memory"); \
                        __builtin_amdgcn_sched_barrier(0); } while (0)
#define WAIT_LGKM0 do { asm volatile("s_waitcnt lgkmcnt(0)" ::: "memory"); \
                        __builtin_amdgcn_sched_barrier(0); } while (0)

// ---- merged prep: waves 0..8191 build UV rows; waves 8192..9215 build Wcat --
// UV[n][a] = cv_k ; UV[n][768+a] = -2*Wk*cv_k   (t3 dropped: row-constant
// shift cancels exactly in log-softmax). Wcat[c][a]=W^2 ; Wcat[c][768+a]=W.
__global__ void prep(const float* __restrict__ W, const float* __restrict__ CV,
                     const int* __restrict__ labels,
                     __bf16* __restrict__ UV, __bf16* __restrict__ Wcat,
                     int* __restrict__ counter) {
    if (blockIdx.x == 0 && threadIdx.x == 0) *counter = 0;  // for softmax's last-block detect
    int gw   = (blockIdx.x * blockDim.x + threadIdx.x) >> 6;
    int lane = threadIdx.x & 63;
    if (gw < N_SAMPLES) {
        int lab = labels[gw];
        const float* wr = W  + (size_t)lab * A_DIM;
        const float* cr = CV + (size_t)lab * A_DIM;
        #pragma unroll
        for (int p = 0; p < 3; ++p) {
            int a = p * 256 + lane * 4;
            f32x4 wk = *reinterpret_cast<const f32x4*>(wr + a);
            f32x4 cv = *reinterpret_cast<const f32x4*>(cr + a);
            bf16x4 u, v;
            #pragma unroll
            for (int j = 0; j < 4; ++j) {
                u[j] = (__bf16)cv[j];
                v[j] = (__bf16)(-2.0f * wk[j] * cv[j]);
            }
            *reinterpret_cast<bf16x4*>(UV + (size_t)gw * K_DIM + a)         = u;
            *reinterpret_cast<bf16x4*>(UV + (size_t)gw * K_DIM + A_DIM + a) = v;
        }
    } else {
        int c = gw - N_SAMPLES;          // 0..1023
        if (c < N_CLASSES) {
            #pragma unroll
            for (int p = 0; p < 3; ++p) {
                int a = p * 256 + lane * 4;
                f32x4 w = *reinterpret_cast<const f32x4*>(W + (size_t)c * A_DIM + a);
                bf16x4 sq, li;
                #pragma unroll
                for (int j = 0; j < 4; ++j) { sq[j] = (__bf16)(w[j] * w[j]); li[j] = (__bf16)w[j]; }
                *reinterpret_cast<bf16x4*>(Wcat + (size_t)c * K_DIM + a)         = sq;
                *reinterpret_cast<bf16x4*>(Wcat + (size_t)c * K_DIM + A_DIM + a) = li;
            }
        } else {
            bf16x4 z = {(__bf16)0.f, (__bf16)0.f, (__bf16)0.f, (__bf16)0.f};
            #pragma unroll
            for (int p = 0; p < 6; ++p)
                *reinterpret_cast<bf16x4*>(Wcat + (size_t)c * K_DIM + p * 256 + lane * 4) = z;
        }
    }
}

// ---------------- GEMM: RAW[n][c] = sum_k UV[n,k]*Wcat[c,k]  (t1 - 2*t2) -----
// 256x128 tile, 512 thr (8 waves, 4Mx2N), 3-stage LDS pipeline. m201 phase
// discipline: per phase {ds_read || stage-issue -> barrier -> lgkm0 ->
// setprio MFMA -> barrier}; counted vmcnt(6) once per K-tile (never 0 steady).
// XOR source-swizzle (conflict-free, verified R2); XCD-chunked block swizzle.
__global__ __launch_bounds__(512, 2) void gemm_raw(
        const __bf16* __restrict__ UV, const __bf16* __restrict__ Wcat,
        __bf16* __restrict__ RAW) {
    __shared__ __align__(16) __bf16 As[3][BM * BK];   // 3 x 32 KB
    __shared__ __align__(16) __bf16 Bs[3][BN * BK];   // 3 x 16 KB  (144 KB total)
    int tid  = threadIdx.x;
    int lane = tid & 63;
    int wave = tid >> 6;
    // XCD-chunked bijective swizzle: 256 blocks, 8 XCDs, 32 blocks/XCD.
    int wgid = (blockIdx.x & 7) * 32 + (blockIdx.x >> 3);
    int rowTile = wgid >> 3;         // 32 row tiles of 256 samples
    int colTile = wgid & 7;          // 8 col tiles of 128 classes
    int rowBase = rowTile * BM;
    int colBase = colTile * BN;
    int wr = wave >> 1;              // 4x2 wave grid, each wave owns 64x64
    int wc = wave & 1;

    f32x4 acc[4][4];
    #pragma unroll
    for (int m = 0; m < 4; ++m)
        #pragma unroll
        for (int n = 0; n < 4; ++n)
            acc[m][n] = (f32x4){0.f, 0.f, 0.f, 0.f};

    // LDS dest LINEAR (global_load_lds = wave-uniform base + lane*16);
    // swizzle lives in the GLOBAL source chunk index: cch ^ (row&7).
    auto stageA = [&](int b, int k0) {           // 256x64 A-tile: 4 loads/thread
        #pragma unroll
        for (int i = 0; i < 4; ++i) {
            int lin  = i * 512 + tid;
            int row  = lin >> 3;                 // 0..255
            int scch = (lin & 7) ^ (row & 7);
            int base = i * 512 + (tid & ~63);
            const __bf16* ga = UV + (size_t)(rowBase + row) * K_DIM + k0 + scch * 8;
            __builtin_amdgcn_global_load_lds(
                (const __attribute__((address_space(1))) void*)ga,
                (__attribute__((address_space(3))) void*)((char*)&As[b][0] + (size_t)base * 16),
                16, 0, 0);
        }
    };
    auto stageB = [&](int b, int k0) {           // 128x64 B-tile: 2 loads/thread
        #pragma unroll
        for (int i = 0; i < 2; ++i) {
            int lin  = i * 512 + tid;
            int row  = lin >> 3;                 // 0..127
            int scch = (lin & 7) ^ (row & 7);
            int base = i * 512 + (tid & ~63);
            const __bf16* gb = Wcat + (size_t)(colBase + row) * K_DIM + k0 + scch * 8;
            __builtin_amdgcn_global_load_lds(
                (const __attribute__((address_space(1))) void*)gb,
                (__attribute__((address_space(3))) void*)((char*)&Bs[b][0] + (size_t)base * 16),
                16, 0, 0);
        }
    };
    auto loadFrags = [&](int b, int kk, bf16x8* af, bf16x8* bf) {
        int swch = ((kk * 4 + (lane >> 4)) ^ (lane & 7)) * 8;
        #pragma unroll
        for (int m = 0; m < 4; ++m) {
            int r = wr * 64 + m * 16 + (lane & 15);
            af[m] = *reinterpret_cast<const bf16x8*>(&As[b][r * BK + swch]);
        }
        #pragma unroll
        for (int n = 0; n < 4; ++n) {
            int c = wc * 64 + n * 16 + (lane & 15);
            bf[n] = *reinterpret_cast<const bf16x8*>(&Bs[b][c * BK + swch]);
        }
    };
    auto doMFMA = [&](bf16x8* af, bf16x8* bf) {
        __builtin_amdgcn_s_setprio(1);
        #pragma unroll
        for (int m = 0; m < 4; ++m)
            #pragma unroll
            for (int n = 0; n < 4; ++n)
                acc[m][n] = __builtin_amdgcn_mfma_f32_16x16x32_bf16(
                    af[m], bf[n], acc[m][n], 0, 0, 0);
        __builtin_amdgcn_s_setprio(0);
    };

    // prologue: tiles 0,1 staged; wait tile 0 (leave tile 1's 6 in flight)
    stageA(0, 0);        stageB(0, 0);
    stageA(1, BK);       stageB(1, BK);
    WAIT_VM(6);
    __builtin_amdgcn_s_barrier();

    for (int kt = 0; kt < NT; ++kt) {
        int bR = kt % 3;
        int bS = (kt + 2) % 3;
        bool st = (kt + 2) < NT;
        int k2 = (kt + 2) * BK;
        bf16x8 af[4], bf[4];
        // ---- phase 0 (kk=0): reads + A-stage issue, barrier, MFMA, barrier
        loadFrags(bR, 0, af, bf);
        if (st) stageA(bS, k2);
        __builtin_amdgcn_s_barrier();
        WAIT_LGKM0;
        doMFMA(af, bf);
        __builtin_amdgcn_s_barrier();
        // ---- phase 1 (kk=1): reads + B-stage issue, vmcnt boundary, barrier, MFMA, barrier
        loadFrags(bR, 1, af, bf);
        if (st) stageB(bS, k2);
        // in flight: 6 (tile kt+1) + 6 (tile kt+2, just issued) -> keep 6 => tile kt+1 landed
        if (st) { WAIT_VM(6); } else { WAIT_VM(0); }
        __builtin_amdgcn_s_barrier();
        WAIT_LGKM0;
        doMFMA(af, bf);
        __builtin_amdgcn_s_barrier();
    }

    // epilogue: raw dot only. C/D layout col=lane&15, row=(lane>>4)*4+j [m89/m91]
    int lr = (lane >> 4) * 4;
    int lc = lane & 15;
    #pragma unroll
    for (int m = 0; m < 4; ++m) {
        #pragma unroll
        for (int n = 0; n < 4; ++n) {
            int gr0 = rowBase + wr * 64 + m * 16 + lr;
            int gc  = colBase + wc * 64 + n * 16 + lc;
            #pragma unroll
            for (int j = 0; j < 4; ++j)
                RAW[(size_t)(gr0 + j) * C_PAD + gc] = (__bf16)acc[m][n][j];
        }
    }
}

// ------- fused: aug = logits + h*raw; log-softmax NLL; last block reduces ----
// one wave per row (4 rows/block); deterministic final sum in the last block.
__global__ void softmax_loss(const __bf16* __restrict__ RAW,
                             const float* __restrict__ logits,
                             const float* __restrict__ ratiop,
                             const int* __restrict__ labels,
                             float* __restrict__ partial,
                             int* __restrict__ counter,
                             float* __restrict__ out) {
    int tid  = threadIdx.x;
    int lane = tid & 63;
    int wv   = tid >> 6;
    int gw   = blockIdx.x * 4 + wv;
    float h  = 0.5f * ratiop[0];
    const __bf16* rowp = RAW + (size_t)gw * C_PAD;
    const float*  lrow = logits + (size_t)gw * N_CLASSES;

    bf16x8 v0 = *reinterpret_cast<const bf16x8*>(rowp + lane * 8);
    bf16x8 v1 = *reinterpret_cast<const bf16x8*>(rowp + 512 + lane * 8);
    f32x4 l0a = *reinterpret_cast<const f32x4*>(lrow + lane * 8);
    f32x4 l0b = *reinterpret_cast<const f32x4*>(lrow + lane * 8 + 4);
    f32x4 l1a = {0.f,0.f,0.f,0.f}, l1b = {0.f,0.f,0.f,0.f};
    if (lane < 61) {                 // cols 512+lane*8..+7 < 1000 iff lane < 61
        l1a = *reinterpret_cast<const f32x4*>(lrow + 512 + lane * 8);
        l1b = *reinterpret_cast<const f32x4*>(lrow + 512 + lane * 8 + 4);
    }
    float f[16];
    #pragma unroll
    for (int j = 0; j < 4; ++j) {
        f[j]     = l0a[j] + h * (float)v0[j];
        f[4 + j] = l0b[j] + h * (float)v0[4 + j];
    }
    #pragma unroll
    for (int j = 0; j < 4; ++j) {
        f[8 + j]  = (lane < 61) ? l1a[j] + h * (float)v1[j]     : -1e30f;
        f[12 + j] = (lane < 61) ? l1b[j] + h * (float)v1[4 + j] : -1e30f;
    }
    float m = -1e30f;
    #pragma unroll
    for (int j = 0; j < 16; ++j) m = fmaxf(m, f[j]);
    #pragma unroll
    for (int s = 32; s > 0; s >>= 1) m = fmaxf(m, __shfl_xor(m, s));
    float sum = 0.f;
    #pragma unroll
    for (int j = 0; j < 16; ++j) sum += __expf(f[j] - m);
    #pragma unroll
    for (int s = 32; s > 0; s >>= 1) sum += __shfl_xor(sum, s);

    __shared__ float pr[4];
    __shared__ int lastFlag;
    if (lane == 0) {
        int lab = labels[gw];
        float tv = lrow[lab] + h * (float)rowp[lab];
        pr[wv] = logf(sum) + m - tv;
    }
    __syncthreads();
    if (tid == 0) {
        partial[blockIdx.x] = pr[0] + pr[1] + pr[2] + pr[3];
        __threadfence();                               // publish partial
        lastFlag = (atomicAdd(counter, 1) == NBLK_SM - 1);
    }
    __syncthreads();
    if (lastFlag) {
        __threadfence();                               // acquire all partials
        float part = 0.f;
        #pragma unroll
        for (int i = 0; i < NBLK_SM / 256; ++i)
            part += partial[i * 256 + tid];
        #pragma unroll
        for (int s = 32; s > 0; s >>= 1) part += __shfl_xor(part, s);
        __shared__ float tmp[4];
        if (lane == 0) tmp[wv] = part;
        __syncthreads();
        if (tid == 0) {
            out[0] = (tmp[0] + tmp[1] + tmp[2] + tmp[3]) / (float)N_SAMPLES;
            *counter = 0;                              // reset for next replay
        }
    }
}

extern "C" void kernel_launch(void* const* d_in, const int* in_sizes, int n_in,
                              void* d_out, int out_size, void* d_ws, size_t ws_size,
                              hipStream_t stream) {
    const float* W      = (const float*)d_in[0];   // fc_weight [C, A]
    // d_in[1] = features [N, A] — unused by the reference math
    const float* logits = (const float*)d_in[2];   // [N, C]
    const int*   labels = (const int*)d_in[3];     // [N]
    const float* ratio  = (const float*)d_in[4];   // scalar
    const float* CV     = (const float*)d_in[5];   // cv_matrix [C, A]
    // d_in[6] = manner — unused

    // workspace layout (bytes), total ~45.1 MB
    char* ws = (char*)d_ws;
    __bf16* Wcat    = (__bf16*)(ws + 0);            //  3,145,728 B  [1024][1536] bf16
    __bf16* UV      = (__bf16*)(ws + 3145728);      // 25,165,824 B  [8192][1536] bf16
    __bf16* RAW     = (__bf16*)(ws + 28311552);     // 16,777,216 B  [8192][1024] bf16
    float*  partial = (float*) (ws + 45088768);     //      8,192 B  [2048] f32
    int*    counter = (int*)   (ws + 45096960);     //          4 B

    prep<<<(N_SAMPLES + C_PAD) / 4, 256, 0, stream>>>(W, CV, labels, UV, Wcat, counter);
    gemm_raw<<<256, 512, 0, stream>>>(UV, Wcat, RAW);
    softmax_loss<<<NBLK_SM, 256, 0, stream>>>(RAW, logits, ratio, labels,
                                              partial, counter, (float*)d_out);
}

// Round 6
// 57.419 us; speedup vs baseline: 1.7272x; 1.7272x over previous
//
#include <hip/hip_runtime.h>
#include <cstdint>
#include <cstddef>

// Problem constants (reference: N=8192, C=1000, A=768)
#define N_SAMPLES 8192
#define N_CLASSES 1000
#define C_PAD     1024
#define A_DIM     768
#define K_DIM     1536   // 2*A  (concatenated [u ; v] / [W^2 ; W])
#define BM 256
#define BN 128
#define BK 64
#define NT (K_DIM / BK)  // 24 K-steps

typedef __attribute__((ext_vector_type(8))) __bf16 bf16x8;
typedef __attribute__((ext_vector_type(4))) __bf16 bf16x4;
typedef __attribute__((ext_vector_type(4))) float  f32x4;

#define WAIT_VM(N) do { asm volatile("s_waitcnt vmcnt(" #N ")" ::: "memory"); \
                        __builtin_amdgcn_sched_barrier(0); } while (0)
#define WAIT_LGKM0 do { asm volatile("s_waitcnt lgkmcnt(0)" ::: "memory"); \
                        __builtin_amdgcn_sched_barrier(0); } while (0)

// ---- merged prep: waves 0..8191 build UV rows; waves 8192..9215 build Wcat --
// UV[n][a] = cv_k ; UV[n][768+a] = -2*Wk*cv_k   (t3 dropped: row-constant
// shift cancels exactly in log-softmax). Wcat[c][a]=W^2 ; Wcat[c][768+a]=W.
__global__ void prep(const float* __restrict__ W, const float* __restrict__ CV,
                     const int* __restrict__ labels,
                     __bf16* __restrict__ UV, __bf16* __restrict__ Wcat) {
    int gw   = (blockIdx.x * blockDim.x + threadIdx.x) >> 6;
    int lane = threadIdx.x & 63;
    if (gw < N_SAMPLES) {
        int lab = labels[gw];
        const float* wr = W  + (size_t)lab * A_DIM;
        const float* cr = CV + (size_t)lab * A_DIM;
        #pragma unroll
        for (int p = 0; p < 3; ++p) {
            int a = p * 256 + lane * 4;
            f32x4 wk = *reinterpret_cast<const f32x4*>(wr + a);
            f32x4 cv = *reinterpret_cast<const f32x4*>(cr + a);
            bf16x4 u, v;
            #pragma unroll
            for (int j = 0; j < 4; ++j) {
                u[j] = (__bf16)cv[j];
                v[j] = (__bf16)(-2.0f * wk[j] * cv[j]);
            }
            *reinterpret_cast<bf16x4*>(UV + (size_t)gw * K_DIM + a)         = u;
            *reinterpret_cast<bf16x4*>(UV + (size_t)gw * K_DIM + A_DIM + a) = v;
        }
    } else {
        int c = gw - N_SAMPLES;          // 0..1023
        if (c < N_CLASSES) {
            #pragma unroll
            for (int p = 0; p < 3; ++p) {
                int a = p * 256 + lane * 4;
                f32x4 w = *reinterpret_cast<const f32x4*>(W + (size_t)c * A_DIM + a);
                bf16x4 sq, li;
                #pragma unroll
                for (int j = 0; j < 4; ++j) { sq[j] = (__bf16)(w[j] * w[j]); li[j] = (__bf16)w[j]; }
                *reinterpret_cast<bf16x4*>(Wcat + (size_t)c * K_DIM + a)         = sq;
                *reinterpret_cast<bf16x4*>(Wcat + (size_t)c * K_DIM + A_DIM + a) = li;
            }
        } else {
            bf16x4 z = {(__bf16)0.f, (__bf16)0.f, (__bf16)0.f, (__bf16)0.f};
            #pragma unroll
            for (int p = 0; p < 6; ++p)
                *reinterpret_cast<bf16x4*>(Wcat + (size_t)c * K_DIM + p * 256 + lane * 4) = z;
        }
    }
}

// ---------------- GEMM: RAW[n][c] = sum_k UV[n,k]*Wcat[c,k]  (t1 - 2*t2) -----
// 256x128 tile, 512 thr (8 waves, 4Mx2N), 3-stage LDS pipeline. m201 phase
// discipline: per phase {ds_read || stage-issue -> barrier -> lgkm0 ->
// setprio MFMA -> barrier}; counted vmcnt(6) once per K-tile (never 0 steady).
// XOR source-swizzle (conflict-free, verified R2); XCD-chunked block swizzle.
__global__ __launch_bounds__(512, 2) void gemm_raw(
        const __bf16* __restrict__ UV, const __bf16* __restrict__ Wcat,
        __bf16* __restrict__ RAW) {
    __shared__ __align__(16) __bf16 As[3][BM * BK];   // 3 x 32 KB
    __shared__ __align__(16) __bf16 Bs[3][BN * BK];   // 3 x 16 KB  (144 KB total)
    int tid  = threadIdx.x;
    int lane = tid & 63;
    int wave = tid >> 6;
    // XCD-chunked bijective swizzle: 256 blocks, 8 XCDs, 32 blocks/XCD.
    int wgid = (blockIdx.x & 7) * 32 + (blockIdx.x >> 3);
    int rowTile = wgid >> 3;         // 32 row tiles of 256 samples
    int colTile = wgid & 7;          // 8 col tiles of 128 classes
    int rowBase = rowTile * BM;
    int colBase = colTile * BN;
    int wr = wave >> 1;              // 4x2 wave grid, each wave owns 64x64
    int wc = wave & 1;

    f32x4 acc[4][4];
    #pragma unroll
    for (int m = 0; m < 4; ++m)
        #pragma unroll
        for (int n = 0; n < 4; ++n)
            acc[m][n] = (f32x4){0.f, 0.f, 0.f, 0.f};

    // LDS dest LINEAR (global_load_lds = wave-uniform base + lane*16);
    // swizzle lives in the GLOBAL source chunk index: cch ^ (row&7).
    auto stageA = [&](int b, int k0) {           // 256x64 A-tile: 4 loads/thread
        #pragma unroll
        for (int i = 0; i < 4; ++i) {
            int lin  = i * 512 + tid;
            int row  = lin >> 3;                 // 0..255
            int scch = (lin & 7) ^ (row & 7);
            int base = i * 512 + (tid & ~63);
            const __bf16* ga = UV + (size_t)(rowBase + row) * K_DIM + k0 + scch * 8;
            __builtin_amdgcn_global_load_lds(
                (const __attribute__((address_space(1))) void*)ga,
                (__attribute__((address_space(3))) void*)((char*)&As[b][0] + (size_t)base * 16),
                16, 0, 0);
        }
    };
    auto stageB = [&](int b, int k0) {           // 128x64 B-tile: 2 loads/thread
        #pragma unroll
        for (int i = 0; i < 2; ++i) {
            int lin  = i * 512 + tid;
            int row  = lin >> 3;                 // 0..127
            int scch = (lin & 7) ^ (row & 7);
            int base = i * 512 + (tid & ~63);
            const __bf16* gb = Wcat + (size_t)(colBase + row) * K_DIM + k0 + scch * 8;
            __builtin_amdgcn_global_load_lds(
                (const __attribute__((address_space(1))) void*)gb,
                (__attribute__((address_space(3))) void*)((char*)&Bs[b][0] + (size_t)base * 16),
                16, 0, 0);
        }
    };
    auto loadFrags = [&](int b, int kk, bf16x8* af, bf16x8* bf) {
        int swch = ((kk * 4 + (lane >> 4)) ^ (lane & 7)) * 8;
        #pragma unroll
        for (int m = 0; m < 4; ++m) {
            int r = wr * 64 + m * 16 + (lane & 15);
            af[m] = *reinterpret_cast<const bf16x8*>(&As[b][r * BK + swch]);
        }
        #pragma unroll
        for (int n = 0; n < 4; ++n) {
            int c = wc * 64 + n * 16 + (lane & 15);
            bf[n] = *reinterpret_cast<const bf16x8*>(&Bs[b][c * BK + swch]);
        }
    };
    auto doMFMA = [&](bf16x8* af, bf16x8* bf) {
        __builtin_amdgcn_s_setprio(1);
        #pragma unroll
        for (int m = 0; m < 4; ++m)
            #pragma unroll
            for (int n = 0; n < 4; ++n)
                acc[m][n] = __builtin_amdgcn_mfma_f32_16x16x32_bf16(
                    af[m], bf[n], acc[m][n], 0, 0, 0);
        __builtin_amdgcn_s_setprio(0);
    };

    // prologue: tiles 0,1 staged; wait tile 0 (leave tile 1's 6 in flight)
    stageA(0, 0);        stageB(0, 0);
    stageA(1, BK);       stageB(1, BK);
    WAIT_VM(6);
    __builtin_amdgcn_s_barrier();

    for (int kt = 0; kt < NT; ++kt) {
        int bR = kt % 3;
        int bS = (kt + 2) % 3;
        bool st = (kt + 2) < NT;
        int k2 = (kt + 2) * BK;
        bf16x8 af[4], bf[4];
        // ---- phase 0 (kk=0): reads + A-stage issue, barrier, MFMA, barrier
        loadFrags(bR, 0, af, bf);
        if (st) stageA(bS, k2);
        __builtin_amdgcn_s_barrier();
        WAIT_LGKM0;
        doMFMA(af, bf);
        __builtin_amdgcn_s_barrier();
        // ---- phase 1 (kk=1): reads + B-stage issue, vmcnt boundary, barrier, MFMA, barrier
        loadFrags(bR, 1, af, bf);
        if (st) stageB(bS, k2);
        // in flight: 6 (tile kt+1) + 6 (tile kt+2, just issued) -> keep 6 => tile kt+1 landed
        if (st) { WAIT_VM(6); } else { WAIT_VM(0); }
        __builtin_amdgcn_s_barrier();
        WAIT_LGKM0;
        doMFMA(af, bf);
        __builtin_amdgcn_s_barrier();
    }

    // epilogue: raw dot only. C/D layout col=lane&15, row=(lane>>4)*4+j [m89/m91]
    int lr = (lane >> 4) * 4;
    int lc = lane & 15;
    #pragma unroll
    for (int m = 0; m < 4; ++m) {
        #pragma unroll
        for (int n = 0; n < 4; ++n) {
            int gr0 = rowBase + wr * 64 + m * 16 + lr;
            int gc  = colBase + wc * 64 + n * 16 + lc;
            #pragma unroll
            for (int j = 0; j < 4; ++j)
                RAW[(size_t)(gr0 + j) * C_PAD + gc] = (__bf16)acc[m][n][j];
        }
    }
}

// ------- fused: aug = logits + h*raw; log-softmax NLL at label --------------
// one wave per row (4 rows/block); rowloss written per-row, NO device fences.
__global__ void softmax_loss(const __bf16* __restrict__ RAW,
                             const float* __restrict__ logits,
                             const float* __restrict__ ratiop,
                             const int* __restrict__ labels,
                             float* __restrict__ rowloss) {
    int tid  = threadIdx.x;
    int lane = tid & 63;
    int wv   = tid >> 6;
    int gw   = blockIdx.x * 4 + wv;
    float h  = 0.5f * ratiop[0];
    const __bf16* rowp = RAW + (size_t)gw * C_PAD;
    const float*  lrow = logits + (size_t)gw * N_CLASSES;

    bf16x8 v0 = *reinterpret_cast<const bf16x8*>(rowp + lane * 8);
    bf16x8 v1 = *reinterpret_cast<const bf16x8*>(rowp + 512 + lane * 8);
    f32x4 l0a = *reinterpret_cast<const f32x4*>(lrow + lane * 8);
    f32x4 l0b = *reinterpret_cast<const f32x4*>(lrow + lane * 8 + 4);
    f32x4 l1a = {0.f,0.f,0.f,0.f}, l1b = {0.f,0.f,0.f,0.f};
    if (lane < 61) {                 // cols 512+lane*8..+7 < 1000 iff lane < 61
        l1a = *reinterpret_cast<const f32x4*>(lrow + 512 + lane * 8);
        l1b = *reinterpret_cast<const f32x4*>(lrow + 512 + lane * 8 + 4);
    }
    float f[16];
    #pragma unroll
    for (int j = 0; j < 4; ++j) {
        f[j]     = l0a[j] + h * (float)v0[j];
        f[4 + j] = l0b[j] + h * (float)v0[4 + j];
    }
    #pragma unroll
    for (int j = 0; j < 4; ++j) {
        f[8 + j]  = (lane < 61) ? l1a[j] + h * (float)v1[j]     : -1e30f;
        f[12 + j] = (lane < 61) ? l1b[j] + h * (float)v1[4 + j] : -1e30f;
    }
    float m = -1e30f;
    #pragma unroll
    for (int j = 0; j < 16; ++j) m = fmaxf(m, f[j]);
    #pragma unroll
    for (int s = 32; s > 0; s >>= 1) m = fmaxf(m, __shfl_xor(m, s));
    float sum = 0.f;
    #pragma unroll
    for (int j = 0; j < 16; ++j) sum += __expf(f[j] - m);
    #pragma unroll
    for (int s = 32; s > 0; s >>= 1) sum += __shfl_xor(sum, s);
    if (lane == 0) {
        int lab = labels[gw];
        float tv = lrow[lab] + h * (float)rowp[lab];
        rowloss[gw] = logf(sum) + m - tv;
    }
}

// ---------------- deterministic final mean (fixed-order, no atomics) --------
__global__ void finalize(const float* __restrict__ rowloss, float* __restrict__ out) {
    int tid = threadIdx.x;
    float part = 0.f;
    #pragma unroll
    for (int i = 0; i < 8; ++i) part += rowloss[i * 1024 + tid];
    #pragma unroll
    for (int s = 32; s > 0; s >>= 1) part += __shfl_xor(part, s);
    __shared__ float tmp[16];
    int lane = tid & 63, wv = tid >> 6;
    if (lane == 0) tmp[wv] = part;
    __syncthreads();
    if (tid == 0) {
        float sum = 0.f;
        #pragma unroll
        for (int w = 0; w < 16; ++w) sum += tmp[w];
        out[0] = sum / (float)N_SAMPLES;
    }
}

extern "C" void kernel_launch(void* const* d_in, const int* in_sizes, int n_in,
                              void* d_out, int out_size, void* d_ws, size_t ws_size,
                              hipStream_t stream) {
    const float* W      = (const float*)d_in[0];   // fc_weight [C, A]
    // d_in[1] = features [N, A] — unused by the reference math
    const float* logits = (const float*)d_in[2];   // [N, C]
    const int*   labels = (const int*)d_in[3];     // [N]
    const float* ratio  = (const float*)d_in[4];   // scalar
    const float* CV     = (const float*)d_in[5];   // cv_matrix [C, A]
    // d_in[6] = manner — unused

    // workspace layout (bytes), total ~45.1 MB
    char* ws = (char*)d_ws;
    __bf16* Wcat    = (__bf16*)(ws + 0);            //  3,145,728 B  [1024][1536] bf16
    __bf16* UV      = (__bf16*)(ws + 3145728);      // 25,165,824 B  [8192][1536] bf16
    __bf16* RAW     = (__bf16*)(ws + 28311552);     // 16,777,216 B  [8192][1024] bf16
    float*  rowloss = (float*) (ws + 45088768);     //     32,768 B  [8192] f32

    prep<<<(N_SAMPLES + C_PAD) / 4, 256, 0, stream>>>(W, CV, labels, UV, Wcat);
    gemm_raw<<<256, 512, 0, stream>>>(UV, Wcat, RAW);
    softmax_loss<<<N_SAMPLES / 4, 256, 0, stream>>>(RAW, logits, ratio, labels, rowloss);
    finalize<<<1, 1024, 0, stream>>>(rowloss, (float*)d_out);
}